// Round 5
// baseline (683.285 us; speedup 1.0000x reference)
//
#include <hip/hip_runtime.h>
#include <hip/hip_bf16.h>
#include <math.h>

#define QDIM 64
#define KDIM 2
#define NDIM 32
#define MDIM 64
#define EDIM 256
#define DDIM 1024
#define RDIM 200
#define SDIM 8192
#define GCOUNT (QDIM * KDIM * NDIM)  // 4096 groups

typedef short short8_t __attribute__((ext_vector_type(8)));
typedef float f32x4 __attribute__((ext_vector_type(4)));

// tanh(x) = 1 - 2/(1+e^{2x}); saturates correctly, ~1ulp rcp error.
__device__ __forceinline__ float tanh_c(float x) {
    float e = __expf(2.0f * x);
    return 1.0f - 2.0f * __builtin_amdgcn_rcpf(1.0f + e);
}

__device__ __forceinline__ uint32_t f2bf(float f) {  // fp32 -> bf16 bits (RNE)
    uint32_t u = __float_as_uint(f);
    return (u + 0x7fffu + ((u >> 16) & 1u)) >> 16;
}
__device__ __forceinline__ float bf2f(unsigned short h) {
    return __uint_as_float(((uint32_t)h) << 16);
}

// ---------------- fused prologue ----------------
// [0,2048): copy hs->out   [2048,2176): pack Wn   [2176,2432): gq
// [2432,2496): rel_prob    [2496,3520): nv scan (4 groups/block)
__global__ __launch_bounds__(256) void prologue_kernel(
    const float* __restrict__ hs, float* __restrict__ out,
    const float* __restrict__ Wn, short* __restrict__ wnpk,
    const int* __restrict__ gnn_idx, const float* __restrict__ Wq,
    const float* __restrict__ bq, float* __restrict__ gqo,
    const int* __restrict__ rel_idx, const float* __restrict__ Wc,
    const float* __restrict__ bc, float* __restrict__ rel_prob,
    const float* __restrict__ nodes, int* __restrict__ nvarr) {
    const int b = blockIdx.x, t = threadIdx.x;
    __shared__ float row[DDIM];
    __shared__ float arr[256];

    if (b < 2048) {  // copy 32MB
        const float4* src = (const float4*)hs;
        float4* dst = (float4*)out;
        int i = b * 256 + t;
#pragma unroll
        for (int r = 0; r < 4; ++r) dst[i + r * 524288] = src[i + r * 524288];
    } else if (b < 2176) {  // pack Wn -> bf16 B-fragments
        int tid = (b - 2048) * 256 + t;
        int lane = tid & 63, ks = (tid >> 6) & 7, ntg = tid >> 9;
        int low = lane & 15, hi = lane >> 4;
        short8_t o;
#pragma unroll
        for (int j = 0; j < 8; ++j) {
            int k = ks * 32 + hi * 8 + j;
            int d = ntg * 16 + low;
            o[j] = (short)f2bf(Wn[(size_t)k * DDIM + d]);
        }
        *(short8_t*)(wnpk + (size_t)tid * 8) = o;
    } else if (b < 2432) {  // gq
        int bb = b - 2176;
        int q = bb >> 2, seg = bb & 3;
        const float* src = hs + (size_t)gnn_idx[q] * DDIM;
        for (int i = t; i < DDIM; i += 256) row[i] = src[i];
        __syncthreads();
        int d = seg * 256 + t;
        float a = bq[d];
#pragma unroll 8
        for (int k = 0; k < DDIM; ++k) a += row[k] * Wq[(size_t)k * DDIM + d];
        gqo[(size_t)q * DDIM + d] = tanh_c(a);
    } else if (b < 2496) {  // rel_prob
        int q = b - 2432;
        const float* src = hs + (size_t)rel_idx[q] * DDIM;
        for (int i = t; i < DDIM; i += 256) row[i] = src[i];
        __syncthreads();
        float lg = -INFINITY;
        if (t < RDIM) {
            float a = bc[t];
            for (int k = 0; k < DDIM; ++k) a += row[k] * Wc[(size_t)k * RDIM + t];
            lg = a;
        }
        arr[t] = lg;
        __syncthreads();
        for (int s = 128; s > 0; s >>= 1) {
            if (t < s) arr[t] = fmaxf(arr[t], arr[t + s]);
            __syncthreads();
        }
        float mx = arr[0];
        __syncthreads();
        float ex = (t < RDIM) ? __expf(lg - mx) : 0.0f;
        arr[t] = ex;
        __syncthreads();
        for (int s = 128; s > 0; s >>= 1) {
            if (t < s) arr[t] += arr[t + s];
            __syncthreads();
        }
        float sm = arr[0];
        if (t < RDIM) rel_prob[q * RDIM + t] = ex / sm;
    } else {  // nv scan: wave per group
        int g = (b - 2496) * 4 + (t >> 6);
        int lane = t & 63;
        float f0 = nodes[(size_t)g * (MDIM * EDIM) + (size_t)lane * EDIM];
        unsigned long long mk = __ballot(f0 != 0.0f);
        if (lane == 0) nvarr[g] = __popcll(mk);
    }
}

// single-block scatter: glist ordered heavy-first (MT 4,3,2,1).
// Order within a bucket is irrelevant (results keyed by g).
__global__ __launch_bounds__(1024) void scatter_kernel(const int* __restrict__ nvarr,
                                                       int* __restrict__ glist) {
    __shared__ int cnt[4], base[4], cur[4];
    int t = threadIdx.x;
    if (t < 4) cnt[t] = 0;
    __syncthreads();
    int mts[4];
#pragma unroll
    for (int r = 0; r < 4; ++r) {
        int g = t + r * 1024;
        int nv = nvarr[g];
        int mt = (nv + 15) >> 4;
        if (mt < 1) mt = 1;
        mts[r] = mt;
        atomicAdd(&cnt[mt - 1], 1);
    }
    __syncthreads();
    if (t == 0) {
        base[3] = 0;
        base[2] = cnt[3];
        base[1] = cnt[3] + cnt[2];
        base[0] = cnt[3] + cnt[2] + cnt[1];
        cur[0] = cur[1] = cur[2] = cur[3] = 0;
    }
    __syncthreads();
#pragma unroll
    for (int r = 0; r < 4; ++r) {
        int g = t + r * 1024;
        int mt = mts[r];
        int pos = base[mt - 1] + atomicAdd(&cur[mt - 1], 1);
        glist[pos] = g | (mt << 16);
    }
}

// ---------------- phase1: one wave per group, direct-global A fragments ----------------
template <int MT>
__device__ __forceinline__ void wave_body(
    float* scratch, int g, int q, const float* __restrict__ nodes,
    const short* __restrict__ wnpk, const float* __restrict__ bn,
    const float* __restrict__ gq, const float* __restrict__ rel_prob,
    const int* __restrict__ prob_idx, float* __restrict__ gvec,
    float* __restrict__ gden, float* __restrict__ gmx) {
    const int lane = threadIdx.x & 63;
    const int low = lane & 15, hi = lane >> 4;
    constexpr int TAIL = 64 - MT * 16;

    // ---- A fragments straight from global: af[mt][ks][j] = bf16(nodes[g][mt*16+low][ks*32+hi*8+j])
    short8_t af[MT][8];
    {
        const float* srcA = nodes + (size_t)g * (MDIM * EDIM);
#pragma unroll
        for (int mt = 0; mt < MT; ++mt) {
            const float* rowp = srcA + (size_t)(mt * 16 + low) * EDIM + hi * 8;
#pragma unroll
            for (int ks = 0; ks < 8; ++ks) {
                float4 a = *(const float4*)(rowp + ks * 32);
                float4 b = *(const float4*)(rowp + ks * 32 + 4);
                short8_t o;
                o[0] = (short)f2bf(a.x); o[1] = (short)f2bf(a.y);
                o[2] = (short)f2bf(a.z); o[3] = (short)f2bf(a.w);
                o[4] = (short)f2bf(b.x); o[5] = (short)f2bf(b.y);
                o[6] = (short)f2bf(b.z); o[7] = (short)f2bf(b.w);
                af[mt][ks] = o;
            }
        }
    }

    // ---- main loop over 64 d-tiles ----
    float dacc[MT][4];
#pragma unroll
    for (int mt = 0; mt < MT; ++mt)
#pragma unroll
        for (int jj = 0; jj < 4; ++jj) dacc[mt][jj] = 0.f;
    float cpart = 0.f;
    const float* gqrow = gq + (size_t)q * DDIM;
    const short8_t* bb = (const short8_t*)wnpk + lane;
    for (int ntg = 0; ntg < 64; ++ntg) {
        int d = ntg * 16 + low;
        float gqv = gqrow[d];
        float bnv = bn[d];
        cpart += tanh_c(bnv) * gqv;
        f32x4 acc[MT];
#pragma unroll
        for (int mt = 0; mt < MT; ++mt) acc[mt] = (f32x4){0.f, 0.f, 0.f, 0.f};
        const short8_t* bp = bb + (size_t)ntg * 512;
#pragma unroll
        for (int ks = 0; ks < 8; ++ks) {
            short8_t bf = bp[ks * 64];
#pragma unroll
            for (int mt = 0; mt < MT; ++mt)
                acc[mt] = __builtin_amdgcn_mfma_f32_16x16x32_bf16(af[mt][ks], bf, acc[mt], 0, 0, 0);
        }
#pragma unroll
        for (int mt = 0; mt < MT; ++mt)
#pragma unroll
            for (int jj = 0; jj < 4; ++jj)
                dacc[mt][jj] += tanh_c(acc[mt][jj] + bnv) * gqv;
    }

    // ---- reduce over the 16 low-lanes: dots[slot = mt*16 + hi*4 + jj] ----
#pragma unroll
    for (int mt = 0; mt < MT; ++mt)
#pragma unroll
        for (int jj = 0; jj < 4; ++jj) {
            float v = dacc[mt][jj];
            v += __shfl_xor(v, 1);
            v += __shfl_xor(v, 2);
            v += __shfl_xor(v, 4);
            v += __shfl_xor(v, 8);
            dacc[mt][jj] = v;
        }
    float cq;
    {
        float cw = cpart;
#pragma unroll
        for (int off = 32; off > 0; off >>= 1) cw += __shfl_xor(cw, off);
        cq = 0.25f * cw;  // each d duplicated over 4 hi groups
    }

    // ---- wave-local softmax chain with analytic tail ----
    float mx = dacc[0][0];
#pragma unroll
    for (int mt = 0; mt < MT; ++mt)
#pragma unroll
        for (int jj = 0; jj < 4; ++jj) mx = fmaxf(mx, dacc[mt][jj]);
    mx = fmaxf(mx, __shfl_xor(mx, 16));
    mx = fmaxf(mx, __shfl_xor(mx, 32));
    if (TAIL > 0) mx = fmaxf(mx, cq);
    float ex[MT][4];
    float sm = 0.f;
#pragma unroll
    for (int mt = 0; mt < MT; ++mt)
#pragma unroll
        for (int jj = 0; jj < 4; ++jj) {
            ex[mt][jj] = __expf(dacc[mt][jj] - mx);
            sm += ex[mt][jj];
        }
    sm += __shfl_xor(sm, 16);
    sm += __shfl_xor(sm, 32);
    float ext = __expf(cq - mx);
    if (TAIL > 0) sm += (float)TAIL * ext;
    float pr = rel_prob[(size_t)q * RDIM + prob_idx[g]];
    float p10 = pr * 10.0f / sm;
#pragma unroll
    for (int mt = 0; mt < MT; ++mt)
#pragma unroll
        for (int jj = 0; jj < 4; ++jj) ex[mt][jj] *= p10;
    float lgvt = ext * p10;
    float gm = ex[0][0];
#pragma unroll
    for (int mt = 0; mt < MT; ++mt)
#pragma unroll
        for (int jj = 0; jj < 4; ++jj) gm = fmaxf(gm, ex[mt][jj]);
    gm = fmaxf(gm, __shfl_xor(gm, 16));
    gm = fmaxf(gm, __shfl_xor(gm, 32));
    if (TAIL > 0) gm = fmaxf(gm, lgvt);
    float el[MT][4];
    float den = 0.f;
#pragma unroll
    for (int mt = 0; mt < MT; ++mt)
#pragma unroll
        for (int jj = 0; jj < 4; ++jj) {
            el[mt][jj] = __expf(ex[mt][jj] - gm);
            den += el[mt][jj];
        }
    den += __shfl_xor(den, 16);
    den += __shfl_xor(den, 32);
    if (TAIL > 0) den += (float)TAIL * __expf(lgvt - gm);
    if (lane == 0) {
        gden[g] = den;
        gmx[g] = gm;
    }

    // ---- lv[m] = el[slot(m)] * mask[m] via LDS bounce ----
    float* lvarr = scratch;        // 64
    float* mkarr = scratch + 64;   // 64
    float* vb = scratch + 128;     // 256
#pragma unroll
    for (int mt = 0; mt < MT; ++mt)
#pragma unroll
        for (int jj = 0; jj < 4; ++jj) lvarr[mt * 16 + hi * 4 + jj] = el[mt][jj];
    if (hi == 0) {
#pragma unroll
        for (int mt = 0; mt < MT; ++mt) {
            unsigned short s0 = (unsigned short)af[mt][0][0];  // e=0 of row mt*16+low
            mkarr[mt * 16 + low] = ((s0 & 0x7fffu) != 0) ? 1.0f : 0.0f;
        }
    }
    asm volatile("s_waitcnt lgkmcnt(0)" ::: "memory");
    float lvm[MT];
#pragma unroll
    for (int mt = 0; mt < MT; ++mt) lvm[mt] = lvarr[mt * 16 + low] * mkarr[mt * 16 + low];

    // ---- weighted column sum from A-fragments (ks-looped to bound regs) ----
#pragma unroll
    for (int ks = 0; ks < 8; ++ks) {
        float acj[8];
#pragma unroll
        for (int j = 0; j < 8; ++j) acj[j] = 0.f;
#pragma unroll
        for (int mt = 0; mt < MT; ++mt) {
            float lw = lvm[mt];
#pragma unroll
            for (int j = 0; j < 8; ++j)
                acj[j] += bf2f((unsigned short)af[mt][ks][j]) * lw;
        }
#pragma unroll
        for (int j = 0; j < 8; ++j) {
            float a = acj[j];
            a += __shfl_xor(a, 1);
            a += __shfl_xor(a, 2);
            a += __shfl_xor(a, 4);
            a += __shfl_xor(a, 8);
            if (low == 0) vb[ks * 32 + hi * 8 + j] = a;  // e = ks*32 + hi*8 + j
        }
    }
    asm volatile("s_waitcnt lgkmcnt(0)" ::: "memory");
    float4 ov = ((const float4*)vb)[lane];
    *(float4*)(gvec + (size_t)g * EDIM + lane * 4) = ov;
}

__global__ __launch_bounds__(64, 4) void phase1_mfma(
    const float* __restrict__ nodes, const short* __restrict__ wnpk,
    const float* __restrict__ bn, const float* __restrict__ gq,
    const float* __restrict__ rel_prob, const int* __restrict__ prob_idx,
    const int* __restrict__ glist, float* __restrict__ gvec,
    float* __restrict__ gden, float* __restrict__ gmx) {
    __shared__ float scratch[384];
    int pk = glist[blockIdx.x];
    int g = pk & 0xFFFF;
    int mt = pk >> 16;
    int q = g >> 6;  // g / (K*N)
    switch (mt) {
        case 1: wave_body<1>(scratch, g, q, nodes, wnpk, bn, gq, rel_prob, prob_idx, gvec, gden, gmx); break;
        case 2: wave_body<2>(scratch, g, q, nodes, wnpk, bn, gq, rel_prob, prob_idx, gvec, gden, gmx); break;
        case 3: wave_body<3>(scratch, g, q, nodes, wnpk, bn, gq, rel_prob, prob_idx, gvec, gden, gmx); break;
        default: wave_body<4>(scratch, g, q, nodes, wnpk, bn, gq, rel_prob, prob_idx, gvec, gden, gmx); break;
    }
}

// ---------------- combine + out ----------------
__global__ __launch_bounds__(256) void combine_kernel(const float* __restrict__ gvec,
                                                      const float* __restrict__ gden,
                                                      const float* __restrict__ gmx,
                                                      float* __restrict__ memb) {
    int qk = blockIdx.x, t = threadIdx.x;
    __shared__ float sgm[NDIM], sden[NDIM];
    if (t < NDIM) {
        sgm[t] = gmx[qk * NDIM + t];
        sden[t] = gden[qk * NDIM + t];
    }
    __syncthreads();
    float gm = -INFINITY;
    for (int n = 0; n < NDIM; ++n) gm = fmaxf(gm, sgm[n]);
    float gs = 0.f;
    for (int n = 0; n < NDIM; ++n) gs += sden[n] * __expf(sgm[n] - gm);
    float me = 0.f;
    for (int n = 0; n < NDIM; ++n)
        me += gvec[(size_t)(qk * NDIM + n) * EDIM + t] * __expf(sgm[n] - gm);
    memb[(size_t)qk * EDIM + t] = me / (gs * (float)(NDIM * MDIM));
}

__global__ __launch_bounds__(256) void out_kernel(const float* __restrict__ memb,
                                                  const float* __restrict__ Wg,
                                                  const float* __restrict__ bg,
                                                  const int* __restrict__ gnn_idx,
                                                  float* __restrict__ out) {
    int q = blockIdx.x, t = threadIdx.x;
    __shared__ float pooled[EDIM];
    pooled[t] = 0.5f * (memb[(size_t)(q * 2 + 0) * EDIM + t] + memb[(size_t)(q * 2 + 1) * EDIM + t]);
    __syncthreads();
    float4 a = ((const float4*)bg)[t];
    const float4* Wg4 = (const float4*)Wg;
    for (int e = 0; e < EDIM; ++e) {
        float p = pooled[e];
        float4 w = Wg4[(size_t)e * (DDIM / 4) + t];
        a.x += p * w.x; a.y += p * w.y; a.z += p * w.z; a.w += p * w.w;
    }
    float4* op = (float4*)(out + (size_t)gnn_idx[q] * DDIM);
    float4 cur = op[t];
    cur.x += tanh_c(a.x);
    cur.y += tanh_c(a.y);
    cur.z += tanh_c(a.z);
    cur.w += tanh_c(a.w);
    op[t] = cur;
}

extern "C" void kernel_launch(void* const* d_in, const int* in_sizes, int n_in,
                              void* d_out, int out_size, void* d_ws, size_t ws_size,
                              hipStream_t stream) {
    const float* hs = (const float*)d_in[0];
    const float* nodes = (const float*)d_in[1];
    const int* prob_idx = (const int*)d_in[2];
    const int* gnn_idx = (const int*)d_in[3];
    const int* rel_idx = (const int*)d_in[4];
    const float* Wc = (const float*)d_in[5];
    const float* bc = (const float*)d_in[6];
    const float* Wq = (const float*)d_in[7];
    const float* bq = (const float*)d_in[8];
    const float* Wn = (const float*)d_in[9];
    const float* bn = (const float*)d_in[10];
    const float* Wg = (const float*)d_in[11];
    const float* bg = (const float*)d_in[12];
    float* out = (float*)d_out;
    float* ws = (float*)d_ws;

    // ws layout (floats): relprob[16384] | gq[65536] | gvec[1048576] | gden[4096]
    //   | gmax[4096] | memb[32768] | wnpk(bf16 = 131072 floats) | nvarr[4096] | glist[4096]
    float* relprob = ws;
    float* gqbuf = ws + 16384;
    float* gvec = gqbuf + (size_t)QDIM * DDIM;
    float* gdenA = gvec + (size_t)GCOUNT * EDIM;
    float* gmaxA = gdenA + GCOUNT;
    float* membuf = gmaxA + GCOUNT;
    short* wnpk = (short*)(membuf + (size_t)QDIM * KDIM * EDIM);
    int* nvarr = (int*)(wnpk + (size_t)EDIM * DDIM);
    int* glist = nvarr + GCOUNT;

    prologue_kernel<<<3520, 256, 0, stream>>>(hs, out, Wn, wnpk, gnn_idx, Wq, bq,
                                              gqbuf, rel_idx, Wc, bc, relprob,
                                              nodes, nvarr);
    scatter_kernel<<<1, 1024, 0, stream>>>(nvarr, glist);
    phase1_mfma<<<GCOUNT, 64, 0, stream>>>(nodes, wnpk, bn, gqbuf, relprob,
                                           prob_idx, glist, gvec, gdenA, gmaxA);
    combine_kernel<<<QDIM * KDIM, 256, 0, stream>>>(gvec, gdenA, gmaxA, membuf);
    out_kernel<<<QDIM, 256, 0, stream>>>(membuf, Wg, bg, gnn_idx, out);
}

// Round 6
// 345.160 us; speedup vs baseline: 1.9796x; 1.9796x over previous
//
#include <hip/hip_runtime.h>
#include <hip/hip_bf16.h>
#include <math.h>

#define QDIM 64
#define KDIM 2
#define NDIM 32
#define MDIM 64
#define EDIM 256
#define DDIM 1024
#define RDIM 200
#define SDIM 8192
#define GCOUNT (QDIM * KDIM * NDIM)  // 4096 groups

typedef short short8_t __attribute__((ext_vector_type(8)));
typedef float f32x4 __attribute__((ext_vector_type(4)));

// tanh(x) = 1 - 2/(1+e^{2x}); saturates correctly, ~1ulp rcp error.
__device__ __forceinline__ float tanh_c(float x) {
    float e = __expf(2.0f * x);
    return 1.0f - 2.0f * __builtin_amdgcn_rcpf(1.0f + e);
}

__device__ __forceinline__ uint32_t f2bf(float f) {  // fp32 -> bf16 bits (RNE)
    uint32_t u = __float_as_uint(f);
    return (u + 0x7fffu + ((u >> 16) & 1u)) >> 16;
}
__device__ __forceinline__ float bf2f(unsigned short h) {
    return __uint_as_float(((uint32_t)h) << 16);
}

// ---------------- fused prologue ----------------
// [0,2048): copy hs->out   [2048,2176): pack Wn   [2176,2432): gq
// [2432,2496): rel_prob    [2496,3520): nv scan (4 groups/block)
__global__ __launch_bounds__(256) void prologue_kernel(
    const float* __restrict__ hs, float* __restrict__ out,
    const float* __restrict__ Wn, short* __restrict__ wnpk,
    const int* __restrict__ gnn_idx, const float* __restrict__ Wq,
    const float* __restrict__ bq, float* __restrict__ gqo,
    const int* __restrict__ rel_idx, const float* __restrict__ Wc,
    const float* __restrict__ bc, float* __restrict__ rel_prob,
    const float* __restrict__ nodes, int* __restrict__ nvarr) {
    const int b = blockIdx.x, t = threadIdx.x;
    __shared__ float row[DDIM];
    __shared__ float arr[256];

    if (b < 2048) {  // copy 32MB
        const float4* src = (const float4*)hs;
        float4* dst = (float4*)out;
        int i = b * 256 + t;
#pragma unroll
        for (int r = 0; r < 4; ++r) dst[i + r * 524288] = src[i + r * 524288];
    } else if (b < 2176) {  // pack Wn -> bf16 B-fragments
        int tid = (b - 2048) * 256 + t;
        int lane = tid & 63, ks = (tid >> 6) & 7, ntg = tid >> 9;
        int low = lane & 15, hi = lane >> 4;
        short8_t o;
#pragma unroll
        for (int j = 0; j < 8; ++j) {
            int k = ks * 32 + hi * 8 + j;
            int d = ntg * 16 + low;
            o[j] = (short)f2bf(Wn[(size_t)k * DDIM + d]);
        }
        *(short8_t*)(wnpk + (size_t)tid * 8) = o;
    } else if (b < 2432) {  // gq
        int bb = b - 2176;
        int q = bb >> 2, seg = bb & 3;
        const float* src = hs + (size_t)gnn_idx[q] * DDIM;
        for (int i = t; i < DDIM; i += 256) row[i] = src[i];
        __syncthreads();
        int d = seg * 256 + t;
        float a = bq[d];
#pragma unroll 8
        for (int k = 0; k < DDIM; ++k) a += row[k] * Wq[(size_t)k * DDIM + d];
        gqo[(size_t)q * DDIM + d] = tanh_c(a);
    } else if (b < 2496) {  // rel_prob
        int q = b - 2432;
        const float* src = hs + (size_t)rel_idx[q] * DDIM;
        for (int i = t; i < DDIM; i += 256) row[i] = src[i];
        __syncthreads();
        float lg = -INFINITY;
        if (t < RDIM) {
            float a = bc[t];
            for (int k = 0; k < DDIM; ++k) a += row[k] * Wc[(size_t)k * RDIM + t];
            lg = a;
        }
        arr[t] = lg;
        __syncthreads();
        for (int s = 128; s > 0; s >>= 1) {
            if (t < s) arr[t] = fmaxf(arr[t], arr[t + s]);
            __syncthreads();
        }
        float mx = arr[0];
        __syncthreads();
        float ex = (t < RDIM) ? __expf(lg - mx) : 0.0f;
        arr[t] = ex;
        __syncthreads();
        for (int s = 128; s > 0; s >>= 1) {
            if (t < s) arr[t] += arr[t + s];
            __syncthreads();
        }
        float sm = arr[0];
        if (t < RDIM) rel_prob[q * RDIM + t] = ex / sm;
    } else {  // nv scan: wave per group
        int g = (b - 2496) * 4 + (t >> 6);
        int lane = t & 63;
        float f0 = nodes[(size_t)g * (MDIM * EDIM) + (size_t)lane * EDIM];
        unsigned long long mk = __ballot(f0 != 0.0f);
        if (lane == 0) nvarr[g] = __popcll(mk);
    }
}

// ---------------- job packing: per-q bin-pack groups into 4-unit jobs ----------------
// shapes: 0=(4) 1=(3,1) 2=(2,2) 3=(2,1,1) 4=(1,1,1,1); dummy group id = GCOUNT.
// job int4: x = g0 | shape<<20, y=g1, z=g2, w=g3. x<0 = sentinel (no job).
__global__ __launch_bounds__(64) void pack_jobs(const int* __restrict__ nvarr,
                                                int4* __restrict__ glist4) {
    int q = blockIdx.x, t = threadIdx.x;
    __shared__ int lists[4][64];
    __shared__ int cnt[4];
    if (t < 4) cnt[t] = 0;
    __syncthreads();
    int g = q * 64 + t;
    int nv = nvarr[g];
    int mt = (nv + 15) >> 4;
    if (mt < 1) mt = 1;
    if (mt > 4) mt = 4;
    int pos = atomicAdd(&cnt[mt - 1], 1);
    lists[mt - 1][pos] = g;
    __syncthreads();
    if (t == 0) {
        int c1 = cnt[0], c2 = cnt[1], c3 = cnt[2], c4 = cnt[3];
        int i1 = 0, i2 = 0, i3 = 0, i4 = 0, j = 0;
        int4* outp = glist4 + q * 64;
        const int D = GCOUNT;
        while (i4 < c4) outp[j++] = make_int4(lists[3][i4++] | (0 << 20), D, D, D);
        while (i3 < c3) {
            int g1 = (i1 < c1) ? lists[0][i1++] : D;
            outp[j++] = make_int4(lists[2][i3++] | (1 << 20), g1, D, D);
        }
        while (i2 + 1 < c2) {
            int a = lists[1][i2++], b2 = lists[1][i2++];
            outp[j++] = make_int4(a | (2 << 20), b2, D, D);
        }
        if (i2 < c2) {
            int a = lists[1][i2++];
            int b2 = (i1 < c1) ? lists[0][i1++] : D;
            int c = (i1 < c1) ? lists[0][i1++] : D;
            outp[j++] = make_int4(a | (3 << 20), b2, c, D);
        }
        while (i1 < c1) {
            int a = lists[0][i1++];
            int b2 = (i1 < c1) ? lists[0][i1++] : D;
            int c = (i1 < c1) ? lists[0][i1++] : D;
            int d2 = (i1 < c1) ? lists[0][i1++] : D;
            outp[j++] = make_int4(a | (4 << 20), b2, c, d2);
        }
        while (j < 64) outp[j++] = make_int4(-1, -1, -1, -1);
    }
}

// ---------------- phase1: one wave per 4-unit job ----------------
// epilogue per group: masked full-wave reductions over the group's lane range.
template <int U0, int NU>
__device__ __forceinline__ void epi(int g, int q, float (&dacc)[4][4],
                                    short8_t (&af)[4][8], float cq, float* scr,
                                    const float* __restrict__ rel_prob,
                                    const int* __restrict__ prob_idx,
                                    float* __restrict__ gvec, float* __restrict__ gden,
                                    float* __restrict__ gmx, int lane) {
    const int low = lane & 15, hi = lane >> 4;
    constexpr int TAIL = 64 - NU * 16;
    float mx = -INFINITY;
#pragma unroll
    for (int u = U0; u < U0 + NU; ++u)
#pragma unroll
        for (int jj = 0; jj < 4; ++jj) mx = fmaxf(mx, dacc[u][jj]);
    mx = fmaxf(mx, __shfl_xor(mx, 16));
    mx = fmaxf(mx, __shfl_xor(mx, 32));
    if (TAIL > 0) mx = fmaxf(mx, cq);
    float exv[4][4];
    float sm = 0.f;
#pragma unroll
    for (int u = U0; u < U0 + NU; ++u)
#pragma unroll
        for (int jj = 0; jj < 4; ++jj) {
            exv[u][jj] = __expf(dacc[u][jj] - mx);
            sm += exv[u][jj];
        }
    sm += __shfl_xor(sm, 16);
    sm += __shfl_xor(sm, 32);
    float ext = __expf(cq - mx);
    if (TAIL > 0) sm += (float)TAIL * ext;
    float pr = rel_prob[(size_t)q * RDIM + prob_idx[g >= GCOUNT ? 0 : g]];
    float p10 = pr * 10.0f / sm;
#pragma unroll
    for (int u = U0; u < U0 + NU; ++u)
#pragma unroll
        for (int jj = 0; jj < 4; ++jj) exv[u][jj] *= p10;
    float lgvt = ext * p10;
    float gm = -INFINITY;
#pragma unroll
    for (int u = U0; u < U0 + NU; ++u)
#pragma unroll
        for (int jj = 0; jj < 4; ++jj) gm = fmaxf(gm, exv[u][jj]);
    gm = fmaxf(gm, __shfl_xor(gm, 16));
    gm = fmaxf(gm, __shfl_xor(gm, 32));
    if (TAIL > 0) gm = fmaxf(gm, lgvt);
    float elv[4][4];
    float den = 0.f;
#pragma unroll
    for (int u = U0; u < U0 + NU; ++u)
#pragma unroll
        for (int jj = 0; jj < 4; ++jj) {
            elv[u][jj] = __expf(exv[u][jj] - gm);
            den += elv[u][jj];
        }
    den += __shfl_xor(den, 16);
    den += __shfl_xor(den, 32);
    if (TAIL > 0) den += (float)TAIL * __expf(lgvt - gm);
    if (lane == 0) {
        gden[g] = den;
        gmx[g] = gm;
    }
    // lv via LDS bounce (mask already in mkarr)
    float* lvarr = scr;         // 64
    float* mkarr = scr + 64;    // 64
    float* vb = scr + 128;      // 256
    if (low == 0) {
#pragma unroll
        for (int u = U0; u < U0 + NU; ++u)
#pragma unroll
            for (int jj = 0; jj < 4; ++jj) lvarr[u * 16 + hi * 4 + jj] = elv[u][jj];
    }
    asm volatile("s_waitcnt lgkmcnt(0)" ::: "memory");
    float lvm[4];
#pragma unroll
    for (int u = U0; u < U0 + NU; ++u) lvm[u] = lvarr[u * 16 + low] * mkarr[u * 16 + low];
    // weighted column sum from A fragments
#pragma unroll
    for (int ks = 0; ks < 8; ++ks) {
        float acj[8];
#pragma unroll
        for (int j = 0; j < 8; ++j) acj[j] = 0.f;
#pragma unroll
        for (int u = U0; u < U0 + NU; ++u) {
#pragma unroll
            for (int j = 0; j < 8; ++j)
                acj[j] += bf2f((unsigned short)af[u][ks][j]) * lvm[u];
        }
#pragma unroll
        for (int j = 0; j < 8; ++j) {
            float a = acj[j];
            a += __shfl_xor(a, 1);
            a += __shfl_xor(a, 2);
            a += __shfl_xor(a, 4);
            a += __shfl_xor(a, 8);
            if (low == 0) vb[ks * 32 + hi * 8 + j] = a;  // e = ks*32+hi*8+j
        }
    }
    asm volatile("s_waitcnt lgkmcnt(0)" ::: "memory");
    float4 ov = ((const float4*)vb)[lane];
    *(float4*)(gvec + (size_t)g * EDIM + lane * 4) = ov;
    asm volatile("s_waitcnt lgkmcnt(0)" ::: "memory");  // vb reads done before next epi
}

#define STEP(CUR, NXT, NTG)                                                              \
    {                                                                                    \
        int pn_ = (NTG) + 1;                                                             \
        pn_ = pn_ > 63 ? 63 : pn_;                                                       \
        const short8_t* pp_ = bbase + (size_t)pn_ * 512;                                 \
        _Pragma("unroll") for (int ks = 0; ks < 8; ++ks) NXT[ks] = pp_[ks * 64];         \
        int d_ = (NTG)*16 + low;                                                         \
        float gqv_ = gqrow[d_];                                                          \
        float bnv_ = bn[d_];                                                             \
        cpart += tanh_c(bnv_) * gqv_;                                                    \
        f32x4 a0 = {0.f, 0.f, 0.f, 0.f}, a1 = a0, a2 = a0, a3 = a0;                      \
        _Pragma("unroll") for (int ks = 0; ks < 8; ++ks) {                               \
            a0 = __builtin_amdgcn_mfma_f32_16x16x32_bf16(af[0][ks], CUR[ks], a0, 0, 0, 0); \
            a1 = __builtin_amdgcn_mfma_f32_16x16x32_bf16(af[1][ks], CUR[ks], a1, 0, 0, 0); \
            a2 = __builtin_amdgcn_mfma_f32_16x16x32_bf16(af[2][ks], CUR[ks], a2, 0, 0, 0); \
            a3 = __builtin_amdgcn_mfma_f32_16x16x32_bf16(af[3][ks], CUR[ks], a3, 0, 0, 0); \
        }                                                                                \
        _Pragma("unroll") for (int jj = 0; jj < 4; ++jj) {                               \
            dacc[0][jj] += tanh_c(a0[jj] + bnv_) * gqv_;                                 \
            dacc[1][jj] += tanh_c(a1[jj] + bnv_) * gqv_;                                 \
            dacc[2][jj] += tanh_c(a2[jj] + bnv_) * gqv_;                                 \
            dacc[3][jj] += tanh_c(a3[jj] + bnv_) * gqv_;                                 \
        }                                                                                \
    }

__global__ __launch_bounds__(64, 2) void phase1_mfma(
    const float* __restrict__ nodes, const short* __restrict__ wnpk,
    const float* __restrict__ bn, const float* __restrict__ gq,
    const float* __restrict__ rel_prob, const int* __restrict__ prob_idx,
    const int4* __restrict__ glist4, float* __restrict__ gvec,
    float* __restrict__ gden, float* __restrict__ gmx) {
    __shared__ alignas(16) char transit[8192];
    __shared__ float scr[384];
    int4 jb = glist4[blockIdx.x];
    if (jb.x < 0) return;
    const int shape = (jb.x >> 20) & 7;
    const int g0 = jb.x & 0xFFFF, g1 = jb.y, g2 = jb.z, g3 = jb.w;
    const int q = g0 >> 6;
    const int lane = threadIdx.x & 63;
    const int low = lane & 15, hi = lane >> 4;

    // unit -> (group slot, tile) tables per shape: byte = slot | tile<<4
    const unsigned tabs[5] = {0x30201000u, 0x01201000u, 0x11011000u, 0x02011000u,
                              0x03020100u};
    const unsigned tb = tabs[shape];

    // ---- stage 4 units through LDS transit -> A fragments ----
    short8_t af[4][8];
#pragma unroll
    for (int u = 0; u < 4; ++u) {
        int byte_ = (tb >> (u * 8)) & 0xFF;
        int slot = byte_ & 0xF, tile = byte_ >> 4;
        int gs = slot == 0 ? g0 : slot == 1 ? g1 : slot == 2 ? g2 : g3;
        int lg = (gs >= GCOUNT) ? 0 : gs;
        const float4* src = (const float4*)(nodes + ((size_t)lg * MDIM + tile * 16) * EDIM);
#pragma unroll
        for (int i = 0; i < 16; ++i) {
            int idx4 = i * 64 + lane;
            float4 v = src[idx4];
            int r = idx4 >> 6, c4 = idx4 & 63;
            int off = (r * 512 + c4 * 8) ^ ((r & 7) << 4);
            uint32_t w0 = f2bf(v.x) | (f2bf(v.y) << 16);
            uint32_t w1 = f2bf(v.z) | (f2bf(v.w) << 16);
            *(uint2*)(transit + off) = make_uint2(w0, w1);
        }
        asm volatile("s_waitcnt lgkmcnt(0)" ::: "memory");
#pragma unroll
        for (int ks = 0; ks < 8; ++ks) {
            int off = (low * 512 + ks * 64 + hi * 16) ^ ((low & 7) << 4);
            af[u][ks] = *(const short8_t*)(transit + off);
        }
        asm volatile("s_waitcnt lgkmcnt(0)" ::: "memory");
    }

    // ---- main loop: 64 d-tiles, explicit B double-buffer prefetch ----
    float dacc[4][4];
#pragma unroll
    for (int u = 0; u < 4; ++u)
#pragma unroll
        for (int jj = 0; jj < 4; ++jj) dacc[u][jj] = 0.f;
    float cpart = 0.f;
    const float* gqrow = gq + (size_t)q * DDIM;
    const short8_t* bbase = (const short8_t*)wnpk + lane;
    short8_t bA[8], bB[8];
#pragma unroll
    for (int ks = 0; ks < 8; ++ks) bA[ks] = bbase[ks * 64];
    for (int it = 0; it < 32; ++it) {
        STEP(bA, bB, 2 * it);
        STEP(bB, bA, 2 * it + 1);
    }

    // ---- in-wave reduce over the 16 low-lanes (d-columns) ----
#pragma unroll
    for (int u = 0; u < 4; ++u)
#pragma unroll
        for (int jj = 0; jj < 4; ++jj) {
            float v = dacc[u][jj];
            v += __shfl_xor(v, 1);
            v += __shfl_xor(v, 2);
            v += __shfl_xor(v, 4);
            v += __shfl_xor(v, 8);
            dacc[u][jj] = v;
        }
    float cq;
    {
        float cw = cpart;
#pragma unroll
        for (int off = 32; off > 0; off >>= 1) cw += __shfl_xor(cw, off);
        cq = 0.25f * cw;  // each d duplicated over 4 hi groups
    }

    // ---- masks into LDS (needed by epis) ----
    if (hi == 0) {
#pragma unroll
        for (int u = 0; u < 4; ++u) {
            unsigned short s0 = (unsigned short)af[u][0][0];  // e=0 of row low
            (scr + 64)[u * 16 + low] = ((s0 & 0x7fffu) != 0) ? 1.0f : 0.0f;
        }
    }
    asm volatile("s_waitcnt lgkmcnt(0)" ::: "memory");

    // ---- per-group epilogues by shape ----
    switch (shape) {
        case 0:
            epi<0, 4>(g0, q, dacc, af, cq, scr, rel_prob, prob_idx, gvec, gden, gmx, lane);
            break;
        case 1:
            epi<0, 3>(g0, q, dacc, af, cq, scr, rel_prob, prob_idx, gvec, gden, gmx, lane);
            epi<3, 1>(g1, q, dacc, af, cq, scr, rel_prob, prob_idx, gvec, gden, gmx, lane);
            break;
        case 2:
            epi<0, 2>(g0, q, dacc, af, cq, scr, rel_prob, prob_idx, gvec, gden, gmx, lane);
            epi<2, 2>(g1, q, dacc, af, cq, scr, rel_prob, prob_idx, gvec, gden, gmx, lane);
            break;
        case 3:
            epi<0, 2>(g0, q, dacc, af, cq, scr, rel_prob, prob_idx, gvec, gden, gmx, lane);
            epi<2, 1>(g1, q, dacc, af, cq, scr, rel_prob, prob_idx, gvec, gden, gmx, lane);
            epi<3, 1>(g2, q, dacc, af, cq, scr, rel_prob, prob_idx, gvec, gden, gmx, lane);
            break;
        default:
            epi<0, 1>(g0, q, dacc, af, cq, scr, rel_prob, prob_idx, gvec, gden, gmx, lane);
            epi<1, 1>(g1, q, dacc, af, cq, scr, rel_prob, prob_idx, gvec, gden, gmx, lane);
            epi<2, 1>(g2, q, dacc, af, cq, scr, rel_prob, prob_idx, gvec, gden, gmx, lane);
            epi<3, 1>(g3, q, dacc, af, cq, scr, rel_prob, prob_idx, gvec, gden, gmx, lane);
            break;
    }
}

// ---------------- combine + out ----------------
__global__ __launch_bounds__(256) void combine_kernel(const float* __restrict__ gvec,
                                                      const float* __restrict__ gden,
                                                      const float* __restrict__ gmx,
                                                      float* __restrict__ memb) {
    int qk = blockIdx.x, t = threadIdx.x;
    __shared__ float sgm[NDIM], sden[NDIM];
    if (t < NDIM) {
        sgm[t] = gmx[qk * NDIM + t];
        sden[t] = gden[qk * NDIM + t];
    }
    __syncthreads();
    float gm = -INFINITY;
    for (int n = 0; n < NDIM; ++n) gm = fmaxf(gm, sgm[n]);
    float gs = 0.f;
    for (int n = 0; n < NDIM; ++n) gs += sden[n] * __expf(sgm[n] - gm);
    float me = 0.f;
    for (int n = 0; n < NDIM; ++n)
        me += gvec[(size_t)(qk * NDIM + n) * EDIM + t] * __expf(sgm[n] - gm);
    memb[(size_t)qk * EDIM + t] = me / (gs * (float)(NDIM * MDIM));
}

__global__ __launch_bounds__(256) void out_kernel(const float* __restrict__ memb,
                                                  const float* __restrict__ Wg,
                                                  const float* __restrict__ bg,
                                                  const int* __restrict__ gnn_idx,
                                                  float* __restrict__ out) {
    int q = blockIdx.x, t = threadIdx.x;
    __shared__ float pooled[EDIM];
    pooled[t] = 0.5f * (memb[(size_t)(q * 2 + 0) * EDIM + t] + memb[(size_t)(q * 2 + 1) * EDIM + t]);
    __syncthreads();
    float4 a = ((const float4*)bg)[t];
    const float4* Wg4 = (const float4*)Wg;
    for (int e = 0; e < EDIM; ++e) {
        float p = pooled[e];
        float4 w = Wg4[(size_t)e * (DDIM / 4) + t];
        a.x += p * w.x; a.y += p * w.y; a.z += p * w.z; a.w += p * w.w;
    }
    float4* op = (float4*)(out + (size_t)gnn_idx[q] * DDIM);
    float4 cur = op[t];
    cur.x += tanh_c(a.x);
    cur.y += tanh_c(a.y);
    cur.z += tanh_c(a.z);
    cur.w += tanh_c(a.w);
    op[t] = cur;
}

extern "C" void kernel_launch(void* const* d_in, const int* in_sizes, int n_in,
                              void* d_out, int out_size, void* d_ws, size_t ws_size,
                              hipStream_t stream) {
    const float* hs = (const float*)d_in[0];
    const float* nodes = (const float*)d_in[1];
    const int* prob_idx = (const int*)d_in[2];
    const int* gnn_idx = (const int*)d_in[3];
    const int* rel_idx = (const int*)d_in[4];
    const float* Wc = (const float*)d_in[5];
    const float* bc = (const float*)d_in[6];
    const float* Wq = (const float*)d_in[7];
    const float* bq = (const float*)d_in[8];
    const float* Wn = (const float*)d_in[9];
    const float* bn = (const float*)d_in[10];
    const float* Wg = (const float*)d_in[11];
    const float* bg = (const float*)d_in[12];
    float* out = (float*)d_out;
    float* ws = (float*)d_ws;

    // ws layout (floats), 16B-aligned sections:
    // relprob[16384] | gq[65536] | gvec[(4096+1)*256 pad 1048832] | gden[4352]
    // | gmx[4352] | memb[32768] | wnpk(bf16=131072 floats) | nvarr[4096] | glist4[int4 x4096]
    float* relprob = ws;
    float* gqbuf = ws + 16384;
    float* gvec = gqbuf + 65536;                    // 81920
    float* gdenA = gvec + 1048832;                  // 1130752
    float* gmaxA = gdenA + 4352;                    // 1135104
    float* membuf = gmaxA + 4352;                   // 1139456
    short* wnpk = (short*)(membuf + 32768);         // 1172224
    int* nvarr = (int*)(ws + 1303296);
    int4* glist4 = (int4*)(ws + 1307392);

    prologue_kernel<<<3520, 256, 0, stream>>>(hs, out, Wn, wnpk, gnn_idx, Wq, bq,
                                              gqbuf, rel_idx, Wc, bc, relprob,
                                              nodes, nvarr);
    pack_jobs<<<QDIM, 64, 0, stream>>>(nvarr, glist4);
    phase1_mfma<<<GCOUNT, 64, 0, stream>>>(nodes, wnpk, bn, gqbuf, relprob,
                                           prob_idx, glist4, gvec, gdenA, gmaxA);
    combine_kernel<<<QDIM * KDIM, 256, 0, stream>>>(gvec, gdenA, gmaxA, membuf);
    out_kernel<<<QDIM, 256, 0, stream>>>(membuf, Wg, bg, gnn_idx, out);
}

// Round 7
// 300.973 us; speedup vs baseline: 2.2703x; 1.1468x over previous
//
#include <hip/hip_runtime.h>
#include <hip/hip_bf16.h>
#include <math.h>

#define QDIM 64
#define KDIM 2
#define NDIM 32
#define MDIM 64
#define EDIM 256
#define DDIM 1024
#define RDIM 200
#define SDIM 8192
#define GCOUNT (QDIM * KDIM * NDIM)  // 4096 groups

typedef short short8_t __attribute__((ext_vector_type(8)));
typedef float f32x4 __attribute__((ext_vector_type(4)));

// tanh(x) = 1 - 2/(1+e^{2x}); saturates correctly, ~1ulp rcp error.
__device__ __forceinline__ float tanh_c(float x) {
    float e = __expf(2.0f * x);
    return 1.0f - 2.0f * __builtin_amdgcn_rcpf(1.0f + e);
}

__device__ __forceinline__ uint32_t f2bf(float f) {  // fp32 -> bf16 bits (RNE)
    uint32_t u = __float_as_uint(f);
    return (u + 0x7fffu + ((u >> 16) & 1u)) >> 16;
}
__device__ __forceinline__ float bf2f(unsigned short h) {
    return __uint_as_float(((uint32_t)h) << 16);
}

// ---------------- fused prologue ----------------
// [0,2048): copy hs->out   [2048,2176): pack Wn   [2176,2432): gq
// [2432,2496): rel_prob    [2496,3520): nv scan (4 groups/block)
__global__ __launch_bounds__(256) void prologue_kernel(
    const float* __restrict__ hs, float* __restrict__ out,
    const float* __restrict__ Wn, short* __restrict__ wnpk,
    const int* __restrict__ gnn_idx, const float* __restrict__ Wq,
    const float* __restrict__ bq, float* __restrict__ gqo,
    const int* __restrict__ rel_idx, const float* __restrict__ Wc,
    const float* __restrict__ bc, float* __restrict__ rel_prob,
    const float* __restrict__ nodes, int* __restrict__ nvarr) {
    const int b = blockIdx.x, t = threadIdx.x;
    __shared__ float row[DDIM];
    __shared__ float arr[256];

    if (b < 2048) {  // copy 32MB
        const float4* src = (const float4*)hs;
        float4* dst = (float4*)out;
        int i = b * 256 + t;
#pragma unroll
        for (int r = 0; r < 4; ++r) dst[i + r * 524288] = src[i + r * 524288];
    } else if (b < 2176) {  // pack Wn -> bf16 B-fragments
        int tid = (b - 2048) * 256 + t;
        int lane = tid & 63, ks = (tid >> 6) & 7, ntg = tid >> 9;
        int low = lane & 15, hi = lane >> 4;
        short8_t o;
#pragma unroll
        for (int j = 0; j < 8; ++j) {
            int k = ks * 32 + hi * 8 + j;
            int d = ntg * 16 + low;
            o[j] = (short)f2bf(Wn[(size_t)k * DDIM + d]);
        }
        *(short8_t*)(wnpk + (size_t)tid * 8) = o;
    } else if (b < 2432) {  // gq
        int bb = b - 2176;
        int q = bb >> 2, seg = bb & 3;
        const float* src = hs + (size_t)gnn_idx[q] * DDIM;
        for (int i = t; i < DDIM; i += 256) row[i] = src[i];
        __syncthreads();
        int d = seg * 256 + t;
        float a = bq[d];
#pragma unroll 8
        for (int k = 0; k < DDIM; ++k) a += row[k] * Wq[(size_t)k * DDIM + d];
        gqo[(size_t)q * DDIM + d] = tanh_c(a);
    } else if (b < 2496) {  // rel_prob
        int q = b - 2432;
        const float* src = hs + (size_t)rel_idx[q] * DDIM;
        for (int i = t; i < DDIM; i += 256) row[i] = src[i];
        __syncthreads();
        float lg = -INFINITY;
        if (t < RDIM) {
            float a = bc[t];
            for (int k = 0; k < DDIM; ++k) a += row[k] * Wc[(size_t)k * RDIM + t];
            lg = a;
        }
        arr[t] = lg;
        __syncthreads();
        for (int s = 128; s > 0; s >>= 1) {
            if (t < s) arr[t] = fmaxf(arr[t], arr[t + s]);
            __syncthreads();
        }
        float mx = arr[0];
        __syncthreads();
        float ex = (t < RDIM) ? __expf(lg - mx) : 0.0f;
        arr[t] = ex;
        __syncthreads();
        for (int s = 128; s > 0; s >>= 1) {
            if (t < s) arr[t] += arr[t + s];
            __syncthreads();
        }
        float sm = arr[0];
        if (t < RDIM) rel_prob[q * RDIM + t] = ex / sm;
    } else {  // nv scan: wave per group
        int g = (b - 2496) * 4 + (t >> 6);
        int lane = t & 63;
        float f0 = nodes[(size_t)g * (MDIM * EDIM) + (size_t)lane * EDIM];
        unsigned long long mk = __ballot(f0 != 0.0f);
        if (lane == 0) nvarr[g] = __popcll(mk);
    }
}

// ---------------- job packing + cq[q] ----------------
// shapes: 0=(4) 1=(3,1) 2=(2,2) 3=(2,1,1) 4=(1,1,1,1); dummy group id = GCOUNT.
__global__ __launch_bounds__(64) void pack_jobs(const int* __restrict__ nvarr,
                                                const float* __restrict__ bn,
                                                const float* __restrict__ gq,
                                                int4* __restrict__ glist4,
                                                float* __restrict__ cqarr) {
    int q = blockIdx.x, t = threadIdx.x;
    __shared__ int lists[4][64];
    __shared__ int cnt[4];
    // cq[q] = sum_d tanh(bn[d]) * gq[q][d]
    float cp = 0.f;
#pragma unroll
    for (int i = 0; i < 16; ++i) {
        int d = i * 64 + t;
        cp += tanh_c(bn[d]) * gq[(size_t)q * DDIM + d];
    }
#pragma unroll
    for (int off = 32; off > 0; off >>= 1) cp += __shfl_xor(cp, off);
    if (t == 0) cqarr[q] = cp;

    if (t < 4) cnt[t] = 0;
    __syncthreads();
    int g = q * 64 + t;
    int nv = nvarr[g];
    int mt = (nv + 15) >> 4;
    if (mt < 1) mt = 1;
    if (mt > 4) mt = 4;
    int pos = atomicAdd(&cnt[mt - 1], 1);
    lists[mt - 1][pos] = g;
    __syncthreads();
    if (t == 0) {
        int c1 = cnt[0], c2 = cnt[1], c3 = cnt[2], c4 = cnt[3];
        int i1 = 0, i2 = 0, i3 = 0, i4 = 0, j = 0;
        int4* outp = glist4 + q * 64;
        const int D = GCOUNT;
        while (i4 < c4) outp[j++] = make_int4(lists[3][i4++] | (0 << 20), D, D, D);
        while (i3 < c3) {
            int g1 = (i1 < c1) ? lists[0][i1++] : D;
            outp[j++] = make_int4(lists[2][i3++] | (1 << 20), g1, D, D);
        }
        while (i2 + 1 < c2) {
            int a = lists[1][i2++], b2 = lists[1][i2++];
            outp[j++] = make_int4(a | (2 << 20), b2, D, D);
        }
        if (i2 < c2) {
            int a = lists[1][i2++];
            int b2 = (i1 < c1) ? lists[0][i1++] : D;
            int c = (i1 < c1) ? lists[0][i1++] : D;
            outp[j++] = make_int4(a | (3 << 20), b2, c, D);
        }
        while (i1 < c1) {
            int a = lists[0][i1++];
            int b2 = (i1 < c1) ? lists[0][i1++] : D;
            int c = (i1 < c1) ? lists[0][i1++] : D;
            int d2 = (i1 < c1) ? lists[0][i1++] : D;
            outp[j++] = make_int4(a | (4 << 20), b2, c, d2);
        }
        while (j < 64) outp[j++] = make_int4(-1, -1, -1, -1);
    }
}

// ---------------- phase1: one wave per 4-unit job ----------------
// epilogue per group: masked full-wave reductions over the group's lane range.
template <int U0, int NU>
__device__ __forceinline__ void epi(int g, int q, float (&dacc)[4][4],
                                    short8_t (&af)[4][8], float cq, float* scr,
                                    const float* __restrict__ rel_prob,
                                    const int* __restrict__ prob_idx,
                                    float* __restrict__ gvec, float* __restrict__ gden,
                                    float* __restrict__ gmx, int lane) {
    const int low = lane & 15, hi = lane >> 4;
    constexpr int TAIL = 64 - NU * 16;
    float mx = -INFINITY;
#pragma unroll
    for (int u = U0; u < U0 + NU; ++u)
#pragma unroll
        for (int jj = 0; jj < 4; ++jj) mx = fmaxf(mx, dacc[u][jj]);
    mx = fmaxf(mx, __shfl_xor(mx, 16));
    mx = fmaxf(mx, __shfl_xor(mx, 32));
    if (TAIL > 0) mx = fmaxf(mx, cq);
    float exv[4][4];
    float sm = 0.f;
#pragma unroll
    for (int u = U0; u < U0 + NU; ++u)
#pragma unroll
        for (int jj = 0; jj < 4; ++jj) {
            exv[u][jj] = __expf(dacc[u][jj] - mx);
            sm += exv[u][jj];
        }
    sm += __shfl_xor(sm, 16);
    sm += __shfl_xor(sm, 32);
    float ext = __expf(cq - mx);
    if (TAIL > 0) sm += (float)TAIL * ext;
    float pr = rel_prob[(size_t)q * RDIM + prob_idx[g >= GCOUNT ? 0 : g]];
    float p10 = pr * 10.0f / sm;
#pragma unroll
    for (int u = U0; u < U0 + NU; ++u)
#pragma unroll
        for (int jj = 0; jj < 4; ++jj) exv[u][jj] *= p10;
    float lgvt = ext * p10;
    float gm = -INFINITY;
#pragma unroll
    for (int u = U0; u < U0 + NU; ++u)
#pragma unroll
        for (int jj = 0; jj < 4; ++jj) gm = fmaxf(gm, exv[u][jj]);
    gm = fmaxf(gm, __shfl_xor(gm, 16));
    gm = fmaxf(gm, __shfl_xor(gm, 32));
    if (TAIL > 0) gm = fmaxf(gm, lgvt);
    float elv[4][4];
    float den = 0.f;
#pragma unroll
    for (int u = U0; u < U0 + NU; ++u)
#pragma unroll
        for (int jj = 0; jj < 4; ++jj) {
            elv[u][jj] = __expf(exv[u][jj] - gm);
            den += elv[u][jj];
        }
    den += __shfl_xor(den, 16);
    den += __shfl_xor(den, 32);
    if (TAIL > 0) den += (float)TAIL * __expf(lgvt - gm);
    if (lane == 0) {
        gden[g] = den;
        gmx[g] = gm;
    }
    // lv via LDS bounce (mask already in mkarr)
    float* lvarr = scr;         // 64
    float* mkarr = scr + 64;    // 64
    float* vb = scr + 128;      // 256
    if (low == 0) {
#pragma unroll
        for (int u = U0; u < U0 + NU; ++u)
#pragma unroll
            for (int jj = 0; jj < 4; ++jj) lvarr[u * 16 + hi * 4 + jj] = elv[u][jj];
    }
    asm volatile("s_waitcnt lgkmcnt(0)" ::: "memory");
    float lvm[4];
#pragma unroll
    for (int u = U0; u < U0 + NU; ++u) lvm[u] = lvarr[u * 16 + low] * mkarr[u * 16 + low];
    // weighted column sum from A fragments
#pragma unroll
    for (int ks = 0; ks < 8; ++ks) {
        float acj[8];
#pragma unroll
        for (int j = 0; j < 8; ++j) acj[j] = 0.f;
#pragma unroll
        for (int u = U0; u < U0 + NU; ++u) {
#pragma unroll
            for (int j = 0; j < 8; ++j)
                acj[j] += bf2f((unsigned short)af[u][ks][j]) * lvm[u];
        }
#pragma unroll
        for (int j = 0; j < 8; ++j) {
            float a = acj[j];
            a += __shfl_xor(a, 1);
            a += __shfl_xor(a, 2);
            a += __shfl_xor(a, 4);
            a += __shfl_xor(a, 8);
            if (low == 0) vb[ks * 32 + hi * 8 + j] = a;  // e = ks*32+hi*8+j
        }
    }
    asm volatile("s_waitcnt lgkmcnt(0)" ::: "memory");
    float4 ov = ((const float4*)vb)[lane];
    *(float4*)(gvec + (size_t)g * EDIM + lane * 4) = ov;
    asm volatile("s_waitcnt lgkmcnt(0)" ::: "memory");  // vb reads done before next epi
}

// per-iter vmem = ONLY the 8 B prefetch loads (operands come from LDS pairs),
// so the compiler's counted wait leaves the prefetch batch in flight.
#define STEP(CUR, NXT, NTG)                                                              \
    {                                                                                    \
        int pn_ = (NTG) + 1;                                                             \
        pn_ = pn_ > 63 ? 63 : pn_;                                                       \
        const short8_t* pp_ = bbase + (size_t)pn_ * 512;                                 \
        _Pragma("unroll") for (int ks = 0; ks < 8; ++ks) NXT[ks] = pp_[ks * 64];         \
        float2 pv_ = pairs[(NTG) * 16 + low];                                            \
        f32x4 a0 = {0.f, 0.f, 0.f, 0.f}, a1 = a0, a2 = a0, a3 = a0;                      \
        _Pragma("unroll") for (int ks = 0; ks < 8; ++ks) {                               \
            a0 = __builtin_amdgcn_mfma_f32_16x16x32_bf16(af[0][ks], CUR[ks], a0, 0, 0, 0); \
            a1 = __builtin_amdgcn_mfma_f32_16x16x32_bf16(af[1][ks], CUR[ks], a1, 0, 0, 0); \
            a2 = __builtin_amdgcn_mfma_f32_16x16x32_bf16(af[2][ks], CUR[ks], a2, 0, 0, 0); \
            a3 = __builtin_amdgcn_mfma_f32_16x16x32_bf16(af[3][ks], CUR[ks], a3, 0, 0, 0); \
        }                                                                                \
        float bnv_ = pv_.x, gqv_ = pv_.y;                                                \
        _Pragma("unroll") for (int jj = 0; jj < 4; ++jj) {                               \
            dacc[0][jj] += tanh_c(a0[jj] + bnv_) * gqv_;                                 \
            dacc[1][jj] += tanh_c(a1[jj] + bnv_) * gqv_;                                 \
            dacc[2][jj] += tanh_c(a2[jj] + bnv_) * gqv_;                                 \
            dacc[3][jj] += tanh_c(a3[jj] + bnv_) * gqv_;                                 \
        }                                                                                \
    }

__global__ __launch_bounds__(64, 2) void phase1_mfma(
    const float* __restrict__ nodes, const short* __restrict__ wnpk,
    const float* __restrict__ bn, const float* __restrict__ gq,
    const float* __restrict__ rel_prob, const int* __restrict__ prob_idx,
    const int4* __restrict__ glist4, const float* __restrict__ cqarr,
    float* __restrict__ gvec, float* __restrict__ gden, float* __restrict__ gmx) {
    __shared__ alignas(16) char transit[8192];
    __shared__ float scr[384];
    int4 jb = glist4[blockIdx.x];
    if (jb.x < 0) return;
    const int shape = (jb.x >> 20) & 7;
    const int g0 = jb.x & 0xFFFF, g1 = jb.y, g2 = jb.z, g3 = jb.w;
    const int q = g0 >> 6;
    const int lane = threadIdx.x & 63;
    const int low = lane & 15, hi = lane >> 4;
    const float cqv = cqarr[q];

    // unit -> (group slot, tile) tables per shape: byte = slot | tile<<4
    const unsigned tabs[5] = {0x30201000u, 0x01201000u, 0x11011000u, 0x02011000u,
                              0x03020100u};
    const unsigned tb = tabs[shape];

    // ---- stage 4 units through LDS transit -> A fragments ----
    short8_t af[4][8];
#pragma unroll
    for (int u = 0; u < 4; ++u) {
        int byte_ = (tb >> (u * 8)) & 0xFF;
        int slot = byte_ & 0xF, tile = byte_ >> 4;
        int gs = slot == 0 ? g0 : slot == 1 ? g1 : slot == 2 ? g2 : g3;
        int lg = (gs >= GCOUNT) ? 0 : gs;
        const float4* src = (const float4*)(nodes + ((size_t)lg * MDIM + tile * 16) * EDIM);
#pragma unroll
        for (int i = 0; i < 16; ++i) {
            int idx4 = i * 64 + lane;
            float4 v = src[idx4];
            int r = idx4 >> 6, c4 = idx4 & 63;
            int off = (r * 512 + c4 * 8) ^ ((r & 7) << 4);
            uint32_t w0 = f2bf(v.x) | (f2bf(v.y) << 16);
            uint32_t w1 = f2bf(v.z) | (f2bf(v.w) << 16);
            *(uint2*)(transit + off) = make_uint2(w0, w1);
        }
        asm volatile("s_waitcnt lgkmcnt(0)" ::: "memory");
#pragma unroll
        for (int ks = 0; ks < 8; ++ks) {
            int off = (low * 512 + ks * 64 + hi * 16) ^ ((low & 7) << 4);
            af[u][ks] = *(const short8_t*)(transit + off);
        }
        asm volatile("s_waitcnt lgkmcnt(0)" ::: "memory");
    }

    // ---- stage (bn, gq) pairs into transit (A staging done) ----
    {
        const float* gqrow = gq + (size_t)q * DDIM;
        float2* pw = (float2*)transit;
#pragma unroll
        for (int i = 0; i < 16; ++i) {
            int d = i * 64 + lane;
            float2 v;
            v.x = bn[d];
            v.y = gqrow[d];
            pw[d] = v;
        }
        asm volatile("s_waitcnt lgkmcnt(0)" ::: "memory");
    }
    const float2* pairs = (const float2*)transit;

    // ---- main loop: 64 d-tiles, explicit B double-buffer prefetch ----
    float dacc[4][4];
#pragma unroll
    for (int u = 0; u < 4; ++u)
#pragma unroll
        for (int jj = 0; jj < 4; ++jj) dacc[u][jj] = 0.f;
    const short8_t* bbase = (const short8_t*)wnpk + lane;
    short8_t bA[8], bB[8];
#pragma unroll
    for (int ks = 0; ks < 8; ++ks) bA[ks] = bbase[ks * 64];
    for (int it = 0; it < 32; ++it) {
        STEP(bA, bB, 2 * it);
        STEP(bB, bA, 2 * it + 1);
    }

    // ---- in-wave reduce over the 16 low-lanes (d-columns) ----
#pragma unroll
    for (int u = 0; u < 4; ++u)
#pragma unroll
        for (int jj = 0; jj < 4; ++jj) {
            float v = dacc[u][jj];
            v += __shfl_xor(v, 1);
            v += __shfl_xor(v, 2);
            v += __shfl_xor(v, 4);
            v += __shfl_xor(v, 8);
            dacc[u][jj] = v;
        }

    // ---- masks into LDS (needed by epis) ----
    if (hi == 0) {
#pragma unroll
        for (int u = 0; u < 4; ++u) {
            unsigned short s0 = (unsigned short)af[u][0][0];  // e=0 of row low
            (scr + 64)[u * 16 + low] = ((s0 & 0x7fffu) != 0) ? 1.0f : 0.0f;
        }
    }
    asm volatile("s_waitcnt lgkmcnt(0)" ::: "memory");

    // ---- per-group epilogues by shape ----
    switch (shape) {
        case 0:
            epi<0, 4>(g0, q, dacc, af, cqv, scr, rel_prob, prob_idx, gvec, gden, gmx, lane);
            break;
        case 1:
            epi<0, 3>(g0, q, dacc, af, cqv, scr, rel_prob, prob_idx, gvec, gden, gmx, lane);
            epi<3, 1>(g1, q, dacc, af, cqv, scr, rel_prob, prob_idx, gvec, gden, gmx, lane);
            break;
        case 2:
            epi<0, 2>(g0, q, dacc, af, cqv, scr, rel_prob, prob_idx, gvec, gden, gmx, lane);
            epi<2, 2>(g1, q, dacc, af, cqv, scr, rel_prob, prob_idx, gvec, gden, gmx, lane);
            break;
        case 3:
            epi<0, 2>(g0, q, dacc, af, cqv, scr, rel_prob, prob_idx, gvec, gden, gmx, lane);
            epi<2, 1>(g1, q, dacc, af, cqv, scr, rel_prob, prob_idx, gvec, gden, gmx, lane);
            epi<3, 1>(g2, q, dacc, af, cqv, scr, rel_prob, prob_idx, gvec, gden, gmx, lane);
            break;
        default:
            epi<0, 1>(g0, q, dacc, af, cqv, scr, rel_prob, prob_idx, gvec, gden, gmx, lane);
            epi<1, 1>(g1, q, dacc, af, cqv, scr, rel_prob, prob_idx, gvec, gden, gmx, lane);
            epi<2, 1>(g2, q, dacc, af, cqv, scr, rel_prob, prob_idx, gvec, gden, gmx, lane);
            epi<3, 1>(g3, q, dacc, af, cqv, scr, rel_prob, prob_idx, gvec, gden, gmx, lane);
            break;
    }
}

// ---------------- combine + out ----------------
__global__ __launch_bounds__(256) void combine_kernel(const float* __restrict__ gvec,
                                                      const float* __restrict__ gden,
                                                      const float* __restrict__ gmx,
                                                      float* __restrict__ memb) {
    int qk = blockIdx.x, t = threadIdx.x;
    __shared__ float sgm[NDIM], sden[NDIM];
    if (t < NDIM) {
        sgm[t] = gmx[qk * NDIM + t];
        sden[t] = gden[qk * NDIM + t];
    }
    __syncthreads();
    float gm = -INFINITY;
    for (int n = 0; n < NDIM; ++n) gm = fmaxf(gm, sgm[n]);
    float gs = 0.f;
    for (int n = 0; n < NDIM; ++n) gs += sden[n] * __expf(sgm[n] - gm);
    float me = 0.f;
    for (int n = 0; n < NDIM; ++n)
        me += gvec[(size_t)(qk * NDIM + n) * EDIM + t] * __expf(sgm[n] - gm);
    memb[(size_t)qk * EDIM + t] = me / (gs * (float)(NDIM * MDIM));
}

__global__ __launch_bounds__(256) void out_kernel(const float* __restrict__ memb,
                                                  const float* __restrict__ Wg,
                                                  const float* __restrict__ bg,
                                                  const int* __restrict__ gnn_idx,
                                                  float* __restrict__ out) {
    int q = blockIdx.x, t = threadIdx.x;
    __shared__ float pooled[EDIM];
    pooled[t] = 0.5f * (memb[(size_t)(q * 2 + 0) * EDIM + t] + memb[(size_t)(q * 2 + 1) * EDIM + t]);
    __syncthreads();
    float4 a = ((const float4*)bg)[t];
    const float4* Wg4 = (const float4*)Wg;
    for (int e = 0; e < EDIM; ++e) {
        float p = pooled[e];
        float4 w = Wg4[(size_t)e * (DDIM / 4) + t];
        a.x += p * w.x; a.y += p * w.y; a.z += p * w.z; a.w += p * w.w;
    }
    float4* op = (float4*)(out + (size_t)gnn_idx[q] * DDIM);
    float4 cur = op[t];
    cur.x += tanh_c(a.x);
    cur.y += tanh_c(a.y);
    cur.z += tanh_c(a.z);
    cur.w += tanh_c(a.w);
    op[t] = cur;
}

extern "C" void kernel_launch(void* const* d_in, const int* in_sizes, int n_in,
                              void* d_out, int out_size, void* d_ws, size_t ws_size,
                              hipStream_t stream) {
    const float* hs = (const float*)d_in[0];
    const float* nodes = (const float*)d_in[1];
    const int* prob_idx = (const int*)d_in[2];
    const int* gnn_idx = (const int*)d_in[3];
    const int* rel_idx = (const int*)d_in[4];
    const float* Wc = (const float*)d_in[5];
    const float* bc = (const float*)d_in[6];
    const float* Wq = (const float*)d_in[7];
    const float* bq = (const float*)d_in[8];
    const float* Wn = (const float*)d_in[9];
    const float* bn = (const float*)d_in[10];
    const float* Wg = (const float*)d_in[11];
    const float* bg = (const float*)d_in[12];
    float* out = (float*)d_out;
    float* ws = (float*)d_ws;

    // ws layout (floats), 16B-aligned sections:
    // relprob[16384] | gq[65536] | gvec[(4096+1)*256 = 1048832] | gden[4352]
    // | gmx[4352] | memb[32768] | wnpk(bf16=131072 floats) | nvarr[4096]
    // | glist4[int4 x4096 = 16384] | cqarr[64]
    float* relprob = ws;
    float* gqbuf = ws + 16384;
    float* gvec = gqbuf + 65536;                    // 81920
    float* gdenA = gvec + 1048832;                  // 1130752
    float* gmaxA = gdenA + 4352;                    // 1135104
    float* membuf = gmaxA + 4352;                   // 1139456
    short* wnpk = (short*)(membuf + 32768);         // 1172224
    int* nvarr = (int*)(ws + 1303296);
    int4* glist4 = (int4*)(ws + 1307392);
    float* cqarr = ws + 1323776;

    prologue_kernel<<<3520, 256, 0, stream>>>(hs, out, Wn, wnpk, gnn_idx, Wq, bq,
                                              gqbuf, rel_idx, Wc, bc, relprob,
                                              nodes, nvarr);
    pack_jobs<<<QDIM, 64, 0, stream>>>(nvarr, bn, gqbuf, glist4, cqarr);
    phase1_mfma<<<GCOUNT, 64, 0, stream>>>(nodes, wnpk, bn, gqbuf, relprob,
                                           prob_idx, glist4, cqarr, gvec, gdenA, gmaxA);
    combine_kernel<<<QDIM * KDIM, 256, 0, stream>>>(gvec, gdenA, gmaxA, membuf);
    out_kernel<<<QDIM, 256, 0, stream>>>(membuf, Wg, bg, gnn_idx, out);
}

// Round 8
// 263.912 us; speedup vs baseline: 2.5891x; 1.1404x over previous
//
#include <hip/hip_runtime.h>
#include <hip/hip_bf16.h>
#include <math.h>

#define QDIM 64
#define KDIM 2
#define NDIM 32
#define MDIM 64
#define EDIM 256
#define DDIM 1024
#define RDIM 200
#define SDIM 8192
#define GCOUNT (QDIM * KDIM * NDIM)  // 4096 groups

typedef short short8_t __attribute__((ext_vector_type(8)));
typedef float f32x4 __attribute__((ext_vector_type(4)));

// tanh(x) = 1 - 2/(1+e^{2x}); saturates correctly, ~1ulp rcp error.
__device__ __forceinline__ float tanh_c(float x) {
    float e = __expf(2.0f * x);
    return 1.0f - 2.0f * __builtin_amdgcn_rcpf(1.0f + e);
}

__device__ __forceinline__ uint32_t f2bf(float f) {  // fp32 -> bf16 bits (RNE)
    uint32_t u = __float_as_uint(f);
    return (u + 0x7fffu + ((u >> 16) & 1u)) >> 16;
}
__device__ __forceinline__ float bf2f(unsigned short h) {
    return __uint_as_float(((uint32_t)h) << 16);
}

// ---------------- fused prologue ----------------
// [0,2048): copy hs->out   [2048,2176): pack Wn   [2176,2432): gq
// [2432,2496): rel_prob    [2496,3520): nv scan (4 groups/block)
__global__ __launch_bounds__(256) void prologue_kernel(
    const float* __restrict__ hs, float* __restrict__ out,
    const float* __restrict__ Wn, short* __restrict__ wnpk,
    const int* __restrict__ gnn_idx, const float* __restrict__ Wq,
    const float* __restrict__ bq, float* __restrict__ gqo,
    const int* __restrict__ rel_idx, const float* __restrict__ Wc,
    const float* __restrict__ bc, float* __restrict__ rel_prob,
    const float* __restrict__ nodes, int* __restrict__ nvarr) {
    const int b = blockIdx.x, t = threadIdx.x;
    __shared__ float row[DDIM];
    __shared__ float arr[256];

    if (b < 2048) {  // copy 32MB
        const float4* src = (const float4*)hs;
        float4* dst = (float4*)out;
        int i = b * 256 + t;
#pragma unroll
        for (int r = 0; r < 4; ++r) dst[i + r * 524288] = src[i + r * 524288];
    } else if (b < 2176) {  // pack Wn -> bf16 B-fragments
        int tid = (b - 2048) * 256 + t;
        int lane = tid & 63, ks = (tid >> 6) & 7, ntg = tid >> 9;
        int low = lane & 15, hi = lane >> 4;
        short8_t o;
#pragma unroll
        for (int j = 0; j < 8; ++j) {
            int k = ks * 32 + hi * 8 + j;
            int d = ntg * 16 + low;
            o[j] = (short)f2bf(Wn[(size_t)k * DDIM + d]);
        }
        *(short8_t*)(wnpk + (size_t)tid * 8) = o;
    } else if (b < 2432) {  // gq
        int bb = b - 2176;
        int q = bb >> 2, seg = bb & 3;
        const float* src = hs + (size_t)gnn_idx[q] * DDIM;
        for (int i = t; i < DDIM; i += 256) row[i] = src[i];
        __syncthreads();
        int d = seg * 256 + t;
        float a = bq[d];
#pragma unroll 8
        for (int k = 0; k < DDIM; ++k) a += row[k] * Wq[(size_t)k * DDIM + d];
        gqo[(size_t)q * DDIM + d] = tanh_c(a);
    } else if (b < 2496) {  // rel_prob
        int q = b - 2432;
        const float* src = hs + (size_t)rel_idx[q] * DDIM;
        for (int i = t; i < DDIM; i += 256) row[i] = src[i];
        __syncthreads();
        float lg = -INFINITY;
        if (t < RDIM) {
            float a = bc[t];
            for (int k = 0; k < DDIM; ++k) a += row[k] * Wc[(size_t)k * RDIM + t];
            lg = a;
        }
        arr[t] = lg;
        __syncthreads();
        for (int s = 128; s > 0; s >>= 1) {
            if (t < s) arr[t] = fmaxf(arr[t], arr[t + s]);
            __syncthreads();
        }
        float mx = arr[0];
        __syncthreads();
        float ex = (t < RDIM) ? __expf(lg - mx) : 0.0f;
        arr[t] = ex;
        __syncthreads();
        for (int s = 128; s > 0; s >>= 1) {
            if (t < s) arr[t] += arr[t + s];
            __syncthreads();
        }
        float sm = arr[0];
        if (t < RDIM) rel_prob[q * RDIM + t] = ex / sm;
    } else {  // nv scan: wave per group
        int g = (b - 2496) * 4 + (t >> 6);
        int lane = t & 63;
        float f0 = nodes[(size_t)g * (MDIM * EDIM) + (size_t)lane * EDIM];
        unsigned long long mk = __ballot(f0 != 0.0f);
        if (lane == 0) nvarr[g] = __popcll(mk);
    }
}

// ---------------- job packing + cq[q] ----------------
// shapes: 0=(4) 1=(3,1) 2=(2,2) 3=(2,1,1) 4=(1,1,1,1); dummy group id = GCOUNT.
__global__ __launch_bounds__(64) void pack_jobs(const int* __restrict__ nvarr,
                                                const float* __restrict__ bn,
                                                const float* __restrict__ gq,
                                                int4* __restrict__ glist4,
                                                float* __restrict__ cqarr) {
    int q = blockIdx.x, t = threadIdx.x;
    __shared__ int lists[4][64];
    __shared__ int cnt[4];
    // cq[q] = sum_d tanh(bn[d]) * gq[q][d]
    float cp = 0.f;
#pragma unroll
    for (int i = 0; i < 16; ++i) {
        int d = i * 64 + t;
        cp += tanh_c(bn[d]) * gq[(size_t)q * DDIM + d];
    }
#pragma unroll
    for (int off = 32; off > 0; off >>= 1) cp += __shfl_xor(cp, off);
    if (t == 0) cqarr[q] = cp;

    if (t < 4) cnt[t] = 0;
    __syncthreads();
    int g = q * 64 + t;
    int nv = nvarr[g];
    int mt = (nv + 15) >> 4;
    if (mt < 1) mt = 1;
    if (mt > 4) mt = 4;
    int pos = atomicAdd(&cnt[mt - 1], 1);
    lists[mt - 1][pos] = g;
    __syncthreads();
    if (t == 0) {
        int c1 = cnt[0], c2 = cnt[1], c3 = cnt[2], c4 = cnt[3];
        int i1 = 0, i2 = 0, i3 = 0, i4 = 0, j = 0;
        int4* outp = glist4 + q * 64;
        const int D = GCOUNT;
        while (i4 < c4) outp[j++] = make_int4(lists[3][i4++] | (0 << 20), D, D, D);
        while (i3 < c3) {
            int g1 = (i1 < c1) ? lists[0][i1++] : D;
            outp[j++] = make_int4(lists[2][i3++] | (1 << 20), g1, D, D);
        }
        while (i2 + 1 < c2) {
            int a = lists[1][i2++], b2 = lists[1][i2++];
            outp[j++] = make_int4(a | (2 << 20), b2, D, D);
        }
        if (i2 < c2) {
            int a = lists[1][i2++];
            int b2 = (i1 < c1) ? lists[0][i1++] : D;
            int c = (i1 < c1) ? lists[0][i1++] : D;
            outp[j++] = make_int4(a | (3 << 20), b2, c, D);
        }
        while (i1 < c1) {
            int a = lists[0][i1++];
            int b2 = (i1 < c1) ? lists[0][i1++] : D;
            int c = (i1 < c1) ? lists[0][i1++] : D;
            int d2 = (i1 < c1) ? lists[0][i1++] : D;
            outp[j++] = make_int4(a | (4 << 20), b2, c, d2);
        }
        while (j < 64) outp[j++] = make_int4(-1, -1, -1, -1);
    }
}

// ---------------- phase1: 4-wave block = 2 jobs; wave owns 2 units ----------------
#define STEP2(CUR, NXT, NTG)                                                               \
    {                                                                                      \
        int pn_ = (NTG) + 1;                                                               \
        pn_ = pn_ > 63 ? 63 : pn_;                                                         \
        const short8_t* pp_ = bbase + (size_t)pn_ * 512;                                   \
        _Pragma("unroll") for (int ks = 0; ks < 8; ++ks) NXT[ks] = pp_[ks * 64];           \
        float2 pv_ = pairs[(NTG)*16 + low];                                                \
        f32x4 a0 = {0.f, 0.f, 0.f, 0.f}, a1 = a0;                                          \
        _Pragma("unroll") for (int ks = 0; ks < 8; ++ks) {                                 \
            a0 = __builtin_amdgcn_mfma_f32_16x16x32_bf16(af[0][ks], CUR[ks], a0, 0, 0, 0); \
            a1 = __builtin_amdgcn_mfma_f32_16x16x32_bf16(af[1][ks], CUR[ks], a1, 0, 0, 0); \
        }                                                                                  \
        float bnv_ = pv_.x, gqv_ = pv_.y;                                                  \
        _Pragma("unroll") for (int jj = 0; jj < 4; ++jj) {                                 \
            dacc[0][jj] += tanh_c(a0[jj] + bnv_) * gqv_;                                   \
            dacc[1][jj] += tanh_c(a1[jj] + bnv_) * gqv_;                                   \
        }                                                                                  \
    }

__global__ __launch_bounds__(256, 3) void phase1_mfma(
    const float* __restrict__ nodes, const short* __restrict__ wnpk,
    const float* __restrict__ bn, const float* __restrict__ gq,
    const float* __restrict__ rel_prob, const int* __restrict__ prob_idx,
    const int4* __restrict__ glist4, const float* __restrict__ cqarr,
    float* __restrict__ gvec, float* __restrict__ gden, float* __restrict__ gmx) {
    __shared__ alignas(16) char transit[4][8192];  // per-wave A staging
    __shared__ float2 pairs[DDIM];                 // (bn, gq) per d, 8KB
    __shared__ float vecu[8][EDIM];                // per-unit weighted sums, 8KB
    __shared__ float dots_s[128];
    __shared__ float lv_s[128];
    __shared__ float mk_s[128];

    const int tid = threadIdx.x;
    const int w = tid >> 6, lane = tid & 63;
    const int low = lane & 15, hi = lane >> 4;

    const int4 jb0 = glist4[2 * blockIdx.x];
    const int4 jb1 = glist4[2 * blockIdx.x + 1];
    if (jb0.x < 0 && jb1.x < 0) return;  // whole block dead (uniform)
    const int4 jb = (w < 2) ? jb0 : jb1;
    const bool live = jb.x >= 0;
    const int q = ((jb0.x >= 0 ? jb0.x : jb1.x) & 0xFFFF) >> 6;
    const float cqv = cqarr[q];

    // unit -> (group slot, tile): byte = slot | tile<<4
    const unsigned tabs[5] = {0x30201000u, 0x01201000u, 0x11011000u, 0x02011000u,
                              0x03020100u};
    const int gA[4] = {jb.x & 0xFFFF, jb.y, jb.z, jb.w};
    const unsigned tb = live ? tabs[(jb.x >> 20) & 7] : 0;

    // ---- stage this wave's 2 units (wave-private transit; no barriers) ----
    int usrc[2] = {GCOUNT, GCOUNT};
    short8_t af[2][8];
    if (live) {
        char* ldsw = transit[w];
#pragma unroll
        for (int u2 = 0; u2 < 2; ++u2) {
            int u = (w & 1) * 2 + u2;
            int byte_ = (tb >> (u * 8)) & 0xFF;
            int slot = byte_ & 0xF, tile = byte_ >> 4;
            int gs = gA[slot];
            usrc[u2] = gs;
            int lg = (gs >= GCOUNT) ? 0 : gs;
            const float4* src =
                (const float4*)(nodes + ((size_t)lg * MDIM + tile * 16) * EDIM);
#pragma unroll
            for (int i = 0; i < 16; ++i) {
                int idx4 = i * 64 + lane;
                float4 v = src[idx4];
                int r = idx4 >> 6, c4 = idx4 & 63;
                int off = (r * 512 + c4 * 8) ^ ((r & 7) << 4);
                uint32_t w0 = f2bf(v.x) | (f2bf(v.y) << 16);
                uint32_t w1 = f2bf(v.z) | (f2bf(v.w) << 16);
                *(uint2*)(ldsw + off) = make_uint2(w0, w1);
            }
            asm volatile("s_waitcnt lgkmcnt(0)" ::: "memory");
#pragma unroll
            for (int ks = 0; ks < 8; ++ks) {
                int off = (low * 512 + ks * 64 + hi * 16) ^ ((low & 7) << 4);
                af[u2][ks] = *(const short8_t*)(ldsw + off);
            }
            asm volatile("s_waitcnt lgkmcnt(0)" ::: "memory");
        }
    }

    // ---- stage (bn,gq) pairs cooperatively ----
    {
        const float* gqrow = gq + (size_t)q * DDIM;
#pragma unroll
        for (int i = 0; i < 4; ++i) {
            int d = tid + i * 256;
            pairs[d] = make_float2(bn[d], gqrow[d]);
        }
    }
    __syncthreads();

    // ---- d-loop: 64 nt-tiles, B double-buffer in regs ----
    float dacc[2][4] = {};
    if (live) {
        const short8_t* bbase = (const short8_t*)wnpk + lane;
        short8_t bA[8], bB[8];
#pragma unroll
        for (int ks = 0; ks < 8; ++ks) bA[ks] = bbase[ks * 64];
        for (int it = 0; it < 32; ++it) {
            STEP2(bA, bB, 2 * it);
            STEP2(bB, bA, 2 * it + 1);
        }
        // in-wave reduce over the 16 low-lanes
#pragma unroll
        for (int u2 = 0; u2 < 2; ++u2)
#pragma unroll
            for (int jj = 0; jj < 4; ++jj) {
                float v = dacc[u2][jj];
                v += __shfl_xor(v, 1);
                v += __shfl_xor(v, 2);
                v += __shfl_xor(v, 4);
                v += __shfl_xor(v, 8);
                dacc[u2][jj] = v;
            }
        if (low == 0) {
#pragma unroll
            for (int u2 = 0; u2 < 2; ++u2)
#pragma unroll
                for (int jj = 0; jj < 4; ++jj)
                    dots_s[(w * 2 + u2) * 16 + hi * 4 + jj] = dacc[u2][jj];
        }
        if (hi == 0) {
#pragma unroll
            for (int u2 = 0; u2 < 2; ++u2) {
                unsigned short s0 = (unsigned short)af[u2][0][0];
                mk_s[(w * 2 + u2) * 16 + low] = ((s0 & 0x7fffu) != 0) ? 1.0f : 0.0f;
            }
        }
    }
    __syncthreads();

    // ---- per-group softmax (groups round-robined over waves) ----
    const int NGT[5] = {1, 2, 2, 3, 4};
    const int U0T[5][4] = {{0, 0, 0, 0}, {0, 3, 0, 0}, {0, 2, 0, 0},
                           {0, 2, 3, 0}, {0, 1, 2, 3}};
    const int NUT[5][4] = {{4, 0, 0, 0}, {3, 1, 0, 0}, {2, 2, 0, 0},
                           {2, 1, 1, 0}, {1, 1, 1, 1}};
    const int ng0 = (jb0.x >= 0) ? NGT[(jb0.x >> 20) & 7] : 0;
    const int ng1 = (jb1.x >= 0) ? NGT[(jb1.x >> 20) & 7] : 0;
    const int ngtot = ng0 + ng1;

    for (int gi = w; gi < ngtot; gi += 4) {
        int jx = (gi < ng0) ? 0 : 1;
        int4 J = jx ? jb1 : jb0;
        int li = jx ? gi - ng0 : gi;
        int shp = (J.x >> 20) & 7;
        int U0 = U0T[shp][li] + jx * 4;
        int NU = NUT[shp][li];
        int gg = (li == 0) ? (J.x & 0xFFFF) : (li == 1) ? J.y : (li == 2) ? J.z : J.w;
        if (gg >= GCOUNT) continue;
        int NS = NU * 16, TL = 64 - NS;
        float dv = (lane < NS) ? dots_s[U0 * 16 + lane] : -INFINITY;
        float mx = dv;
#pragma unroll
        for (int o = 32; o > 0; o >>= 1) mx = fmaxf(mx, __shfl_xor(mx, o));
        if (TL > 0) mx = fmaxf(mx, cqv);
        float ex = (lane < NS) ? __expf(dv - mx) : 0.f;
        float sm = ex;
#pragma unroll
        for (int o = 32; o > 0; o >>= 1) sm += __shfl_xor(sm, o);
        float ext = __expf(cqv - mx);
        if (TL > 0) sm += (float)TL * ext;
        float pr = rel_prob[(size_t)q * RDIM + prob_idx[gg]];
        float p10 = pr * 10.0f / sm;
        float l2 = ex * p10;
        float lgvt = ext * p10;
        float gm = (lane < NS) ? l2 : -INFINITY;
#pragma unroll
        for (int o = 32; o > 0; o >>= 1) gm = fmaxf(gm, __shfl_xor(gm, o));
        if (TL > 0) gm = fmaxf(gm, lgvt);
        float el = (lane < NS) ? __expf(l2 - gm) : 0.f;
        float den = el;
#pragma unroll
        for (int o = 32; o > 0; o >>= 1) den += __shfl_xor(den, o);
        if (TL > 0) den += (float)TL * __expf(lgvt - gm);
        if (lane < NS) lv_s[U0 * 16 + lane] = el * mk_s[U0 * 16 + lane];
        if (lane == 0) {
            gden[gg] = den;
            gmx[gg] = gm;
        }
    }
    __syncthreads();

    // ---- per-unit weighted column sums into vecu ----
    if (live) {
#pragma unroll
        for (int u2 = 0; u2 < 2; ++u2) {
            if (usrc[u2] >= GCOUNT) continue;  // dead unit (wave-uniform)
            int ug = w * 2 + u2;
            float lvm = lv_s[ug * 16 + low];
#pragma unroll
            for (int ks = 0; ks < 8; ++ks) {
                float acj[8];
#pragma unroll
                for (int j = 0; j < 8; ++j)
                    acj[j] = bf2f((unsigned short)af[u2][ks][j]) * lvm;
#pragma unroll
                for (int j = 0; j < 8; ++j) {
                    float a = acj[j];
                    a += __shfl_xor(a, 1);
                    a += __shfl_xor(a, 2);
                    a += __shfl_xor(a, 4);
                    a += __shfl_xor(a, 8);
                    acj[j] = a;
                }
                if (low == 0) {
#pragma unroll
                    for (int j = 0; j < 8; ++j) vecu[ug][ks * 32 + hi * 8 + j] = acj[j];
                }
            }
        }
    }
    __syncthreads();

    // ---- owner waves assemble + store gvec rows ----
    for (int gi = w; gi < ngtot; gi += 4) {
        int jx = (gi < ng0) ? 0 : 1;
        int4 J = jx ? jb1 : jb0;
        int li = jx ? gi - ng0 : gi;
        int shp = (J.x >> 20) & 7;
        int U0 = U0T[shp][li] + jx * 4;
        int NU = NUT[shp][li];
        int gg = (li == 0) ? (J.x & 0xFFFF) : (li == 1) ? J.y : (li == 2) ? J.z : J.w;
        if (gg >= GCOUNT) continue;
#pragma unroll 4
        for (int c = 0; c < 4; ++c) {
            int e = c * 64 + lane;
            float s = 0.f;
            for (int uu = 0; uu < NU; ++uu) s += vecu[U0 + uu][e];
            gvec[(size_t)gg * EDIM + e] = s;
        }
    }
}

// ---------------- combine + out ----------------
__global__ __launch_bounds__(256) void combine_kernel(const float* __restrict__ gvec,
                                                      const float* __restrict__ gden,
                                                      const float* __restrict__ gmx,
                                                      float* __restrict__ memb) {
    int qk = blockIdx.x, t = threadIdx.x;
    __shared__ float sgm[NDIM], sden[NDIM];
    if (t < NDIM) {
        sgm[t] = gmx[qk * NDIM + t];
        sden[t] = gden[qk * NDIM + t];
    }
    __syncthreads();
    float gm = -INFINITY;
    for (int n = 0; n < NDIM; ++n) gm = fmaxf(gm, sgm[n]);
    float gs = 0.f;
    for (int n = 0; n < NDIM; ++n) gs += sden[n] * __expf(sgm[n] - gm);
    float me = 0.f;
    for (int n = 0; n < NDIM; ++n)
        me += gvec[(size_t)(qk * NDIM + n) * EDIM + t] * __expf(sgm[n] - gm);
    memb[(size_t)qk * EDIM + t] = me / (gs * (float)(NDIM * MDIM));
}

__global__ __launch_bounds__(256) void out_kernel(const float* __restrict__ memb,
                                                  const float* __restrict__ Wg,
                                                  const float* __restrict__ bg,
                                                  const int* __restrict__ gnn_idx,
                                                  float* __restrict__ out) {
    int q = blockIdx.x, t = threadIdx.x;
    __shared__ float pooled[EDIM];
    pooled[t] = 0.5f * (memb[(size_t)(q * 2 + 0) * EDIM + t] + memb[(size_t)(q * 2 + 1) * EDIM + t]);
    __syncthreads();
    float4 a = ((const float4*)bg)[t];
    const float4* Wg4 = (const float4*)Wg;
    for (int e = 0; e < EDIM; ++e) {
        float p = pooled[e];
        float4 w = Wg4[(size_t)e * (DDIM / 4) + t];
        a.x += p * w.x; a.y += p * w.y; a.z += p * w.z; a.w += p * w.w;
    }
    float4* op = (float4*)(out + (size_t)gnn_idx[q] * DDIM);
    float4 cur = op[t];
    cur.x += tanh_c(a.x);
    cur.y += tanh_c(a.y);
    cur.z += tanh_c(a.z);
    cur.w += tanh_c(a.w);
    op[t] = cur;
}

extern "C" void kernel_launch(void* const* d_in, const int* in_sizes, int n_in,
                              void* d_out, int out_size, void* d_ws, size_t ws_size,
                              hipStream_t stream) {
    const float* hs = (const float*)d_in[0];
    const float* nodes = (const float*)d_in[1];
    const int* prob_idx = (const int*)d_in[2];
    const int* gnn_idx = (const int*)d_in[3];
    const int* rel_idx = (const int*)d_in[4];
    const float* Wc = (const float*)d_in[5];
    const float* bc = (const float*)d_in[6];
    const float* Wq = (const float*)d_in[7];
    const float* bq = (const float*)d_in[8];
    const float* Wn = (const float*)d_in[9];
    const float* bn = (const float*)d_in[10];
    const float* Wg = (const float*)d_in[11];
    const float* bg = (const float*)d_in[12];
    float* out = (float*)d_out;
    float* ws = (float*)d_ws;

    // ws layout (floats), 16B-aligned sections:
    // relprob[16384] | gq[65536] | gvec[(4096+1)*256 = 1048832] | gden[4352]
    // | gmx[4352] | memb[32768] | wnpk(bf16=131072 floats) | nvarr[4096]
    // | glist4[int4 x4096 = 16384] | cqarr[64]
    float* relprob = ws;
    float* gqbuf = ws + 16384;
    float* gvec = gqbuf + 65536;                    // 81920
    float* gdenA = gvec + 1048832;                  // 1130752
    float* gmaxA = gdenA + 4352;                    // 1135104
    float* membuf = gmaxA + 4352;                   // 1139456
    short* wnpk = (short*)(membuf + 32768);         // 1172224
    int* nvarr = (int*)(ws + 1303296);
    int4* glist4 = (int4*)(ws + 1307392);
    float* cqarr = ws + 1323776;

    prologue_kernel<<<3520, 256, 0, stream>>>(hs, out, Wn, wnpk, gnn_idx, Wq, bq,
                                              gqbuf, rel_idx, Wc, bc, relprob,
                                              nodes, nvarr);
    pack_jobs<<<QDIM, 64, 0, stream>>>(nvarr, bn, gqbuf, glist4, cqarr);
    phase1_mfma<<<GCOUNT / 2, 256, 0, stream>>>(nodes, wnpk, bn, gqbuf, relprob,
                                                prob_idx, glist4, cqarr, gvec, gdenA,
                                                gmaxA);
    combine_kernel<<<QDIM * KDIM, 256, 0, stream>>>(gvec, gdenA, gmaxA, membuf);
    out_kernel<<<QDIM, 256, 0, stream>>>(membuf, Wg, bg, gnn_idx, out);
}